// Round 7
// baseline (666.074 us; speedup 1.0000x reference)
//
#include <hip/hip_runtime.h>
#include <hip/hip_bf16.h>

typedef __attribute__((ext_vector_type(8))) short bf16x8;
typedef __attribute__((ext_vector_type(4))) float f32x4;

__device__ __forceinline__ void async16(const void* g, void* l) {
    __builtin_amdgcn_global_load_lds(
        (const __attribute__((address_space(1))) unsigned int*)g,
        (__attribute__((address_space(3))) unsigned int*)l, 16, 0, 0);
}

// ---------------------------------------------------------------------------
// pack_all: one node = pack_x (10240 blocks) + pack_a (640 blocks).
// [FROZEN]
// ---------------------------------------------------------------------------
__global__ __launch_bounds__(256) void pack_all(const float* __restrict__ x5,
                                                const float* __restrict__ conv_w,
                                                const float* __restrict__ cc_w,
                                                __hip_bfloat16* __restrict__ X3,
                                                __hip_bfloat16* __restrict__ A2f) {
    __shared__ __align__(16) float smem[64 * 65];
    const int f = blockIdx.x;
    if (f < 10240) {
        // ---- pack_x ----
        float(*tile)[65] = (float(*)[65])smem;
        const int ct = f / 1280, r = f % 1280;
        const int wt = r >> 8, bh = r & 255;
        const int b = bh >> 4, h = bh & 15;
        const int w0 = wt * 64, c0 = ct * 64;
        const int lw = (threadIdx.x & 15) * 4;
        const int lc = threadIdx.x >> 4;
#pragma unroll
        for (int i = 0; i < 4; ++i) {
            const int c = lc + i * 16;
            const int w = w0 + lw;
            const float* src = &x5[((size_t)(b * 512 + c0 + c) * 16 + h) * 300 + w];
            float4 v = {0.f, 0.f, 0.f, 0.f};
            if (w + 3 < 300) v = *(const float4*)src;
            else {
                if (w < 300)     v.x = src[0];
                if (w + 1 < 300) v.y = src[1];
                if (w + 2 < 300) v.z = src[2];
            }
            *(float4*)&tile[c][lw] = v;
        }
        __syncthreads();
        const int sc = (threadIdx.x & 7) * 8;     // 8 channels -> 16B store
        const int sw0 = threadIdx.x >> 3;         // 0..31
#pragma unroll
        for (int i = 0; i < 2; ++i) {
            const int wl = sw0 + i * 32;
            const int w = w0 + wl;
            if (w < 300) {
                __hip_bfloat16 p[8];
#pragma unroll
                for (int j = 0; j < 8; ++j) p[j] = __float2bfloat16(tile[sc + j][wl]);
                *(uint4*)&X3[(((size_t)(b * 16 + h) * 300 + w)) * 512 + c0 + sc] = *(uint4*)p;
            }
        }
    } else {
        // ---- pack_a ----
        float* w = smem;
        const int co = f - 10240;                 // 0..639
        if (co < 522) {
            const float4* src = (co < 512) ? (const float4*)(conv_w + (size_t)co * 3584)
                                           : (const float4*)(cc_w + (size_t)(co - 512) * 3584);
            for (int i = threadIdx.x; i < 896; i += 256) *(float4*)&w[i * 4] = src[i];
        } else {
            for (int i = threadIdx.x; i < 3584; i += 256) w[i] = 0.f;
        }
        __syncthreads();
        const int g = co >> 4, fl = co & 15;
        for (int chunk = threadIdx.x; chunk < 448; chunk += 256) {
            const int kk0 = chunk * 8;
            const int kt = kk0 >> 5, sq = (kk0 >> 3) & 3;
            __hip_bfloat16 p[8];
#pragma unroll
            for (int j = 0; j < 8; ++j) {
                const int k = kk0 + j;
                p[j] = __float2bfloat16(w[(k & 511) * 7 + (k >> 9)]);
            }
            char* dst = (char*)A2f + (((size_t)g * 112 + kt) * 64 + sq * 16 + fl) * 16;
            *(uint4*)dst = *(uint4*)p;
        }
    }
}

// ---------------------------------------------------------------------------
// scores_gemm: 10 cc rows, M=16 MFMA, barrier-free + LDS-free staging.
// [FROZEN]
// ---------------------------------------------------------------------------
__global__ __launch_bounds__(256) void scores_gemm(
    const __hip_bfloat16* __restrict__ A2f, const __hip_bfloat16* __restrict__ X3,
    const float* __restrict__ cc_b, float* __restrict__ assign,
    float* __restrict__ asum_part, float* __restrict__ agg) {
    __shared__ float sred[4][4][4];            // [wave][sq][r] asum partials
    const int tid = threadIdx.x;
    const int wv = tid >> 6;
    const int lane = tid & 63;
    const int fl = lane & 15;
    const int sq = lane >> 4;
    const int gid = blockIdx.x;
    const int xcd = gid & 7;
    const int j = gid >> 3;                    // 0..95
    const int b = xcd * 2 + (j >= 48 ? 1 : 0);
    const int nt = j % 48;                     // 64-wide n tile

    // ---- agg zero (81920 floats over 768 blocks) ----
    {
        const int base = gid * 107;
        for (int i = tid; i < 107; i += 256) {
            const int idx = base + i;
            if (idx < 81920) agg[idx] = 0.f;
        }
    }

    const int n = nt * 64 + wv * 16 + fl;
    const int nc = n > 2999 ? 2999 : n;
    const char* gB = (const char*)X3 + ((size_t)(b * 4800 + nc)) * 1024 + sq * 16;
    const char* Af = (const char*)A2f + (((size_t)32 * 112) << 10) + ((size_t)lane << 4);

    f32x4 acc = {};
#pragma unroll 4
    for (int kt = 0; kt < 112; ++kt) {
        const bf16x8 a  = *(const bf16x8*)(Af + ((size_t)kt << 10));
        const bf16x8 bv = *(const bf16x8*)(gB + (size_t)(kt >> 4) * 307200 + (size_t)(kt & 15) * 64);
        acc = __builtin_amdgcn_mfma_f32_16x16x32_bf16(a, bv, acc, 0, 0, 0);
    }

    float s[4];
#pragma unroll
    for (int r = 0; r < 4; ++r) {
        const int k = sq * 4 + r;
        s[r] = (k < 10) ? (acc[r] + cc_b[k]) : -1e30f;
    }
    float mx = fmaxf(fmaxf(s[0], s[1]), fmaxf(s[2], s[3]));
    mx = fmaxf(mx, __shfl_xor(mx, 16, 64));
    mx = fmaxf(mx, __shfl_xor(mx, 32, 64));
    float e[4], es = 0.f;
#pragma unroll
    for (int r = 0; r < 4; ++r) {
        e[r] = (sq * 4 + r < 10) ? __expf(s[r] - mx) : 0.f;
        es += e[r];
    }
    es += __shfl_xor(es, 16, 64);
    es += __shfl_xor(es, 32, 64);
    const float inv = 1.f / es;
    const bool nval = (n < 3000);
    float pa[4];
#pragma unroll
    for (int r = 0; r < 4; ++r) {
        const int k = sq * 4 + r;
        const float a = e[r] * inv;
        pa[r] = nval ? a : 0.f;
        if (nval && k < 10) assign[(size_t)(b * 10 + k) * 3000 + n] = a;
    }
#pragma unroll
    for (int off = 1; off < 16; off <<= 1)
#pragma unroll
        for (int r = 0; r < 4; ++r) pa[r] += __shfl_xor(pa[r], off, 64);
    if (fl == 0) {
#pragma unroll
        for (int r = 0; r < 4; ++r) sred[wv][sq][r] = pa[r];
    }
    __syncthreads();
    if (tid < 10)
        asum_part[(nt * 16 + b) * 10 + tid] =
            sred[0][tid >> 2][tid & 3] + sred[1][tid >> 2][tid & 3] +
            sred[2][tid >> 2][tid & 3] + sred[3][tid >> 2][tid & 3];
}

// ---------------------------------------------------------------------------
// conv_gemm v4: single-barrier free-run schedule.
// R6's 5-barrier lockstep phases serialized LDS reads against MFMA (35%
// MfmaUtil, 224us). v4 keeps R6's staging/swizzle/epilogue verbatim but the
// K-loop is: {16 ds_read -> 32 MFMA (setprio) -> vmcnt(0) -> barrier ->
// STAGE(t+2)}. One barrier per K-tile; waves free-run inside the tile so one
// wave's MFMA overlaps another's ds_reads (the inter-wave overlap the old
// 3-block/CU kernel got for free). Hazard proof:
//  - STAGE(t+2) overwrites buf[t&1]: every wave's reads of buf were consumed
//    by its MFMAs (compiler lgkm waits) before it reaches the barrier ->
//    after the barrier all reads are complete block-wide.
//  - BODY(t+1) reads buf staged by STAGE(t+1): vmcnt(0) before the barrier
//    drains it; those 6 loads are a full K-tile old (~1400cy > 900cy HBM
//    latency) so the wait is ~free and overlaps wave drift.
// K order per acc element unchanged (kk0 then kk1) -> numerics identical.
// Tile 128m x 256n x BK=64, 8 waves, grid 768 = 3 residency rounds @1/CU.
// ---------------------------------------------------------------------------
__global__ __launch_bounds__(512) void conv_gemm(
    const __hip_bfloat16* __restrict__ A2f, const __hip_bfloat16* __restrict__ X3,
    const float* __restrict__ conv_b, const float* __restrict__ assign,
    float* __restrict__ agg) {
    __shared__ __align__(16) char lds[98304];
    const int tid = threadIdx.x;
    const int wv = tid >> 6;                   // 0..7
    const int lane = tid & 63;
    const int fl = lane & 15, sq = lane >> 4;

    const int gid = blockIdx.x;
    const int xcd = gid & 7;
    const int j = gid >> 3;                    // 0..95
    const int u = xcd * 24 + (j >> 2);         // 0..191 (b,nt2)
    const int m0 = (j & 3) * 128;
    const int b = u / 12;
    const int nt2 = u % 12;

    // ---- staging source/dest (lane-static prefixes) ----
    const int l3 = lane >> 3, l7 = lane & 7;
    const int sp = l7 ^ l3;                    // pre-swizzled source slot
    const char* srcB[4];
#pragma unroll
    for (int c = 0; c < 4; ++c) {
        int n = nt2 * 256 + (wv * 4 + c) * 8 + l3;
        if (n > 2999) n = 2999;
        srcB[c] = (const char*)X3 + ((size_t)(b * 4800 + n)) * 1024
                + (sp >> 2) * 64 + (sp & 3) * 16;
    }
    const int gbase = m0 >> 4;
    const char* srcA[2];
#pragma unroll
    for (int c = 0; c < 2; ++c) {
        const int ca = wv * 2 + c;
        srcA[c] = (const char*)A2f + (((size_t)(gbase + (ca >> 1)) * 112 + (ca & 1)) << 10)
                + ((size_t)lane << 4);
    }
    char* dstB = lds + (size_t)(wv * 4) * 1024 + ((size_t)lane << 4);
    char* dstA = lds + 32768 + (size_t)(wv * 2) * 1024 + ((size_t)lane << 4);

    // ---- fragment read offsets ----
    const int wm = (wv & 1) * 64;
    const int wn = (wv >> 1) * 64;
    int bo_[4][2], ao_[4][2];
#pragma unroll
    for (int ni = 0; ni < 4; ++ni)
#pragma unroll
        for (int kk = 0; kk < 2; ++kk) {
            const int r = wn + ni * 16 + fl;   // r&7 == fl&7
            bo_[ni][kk] = r * 128 + ((((kk * 4 + sq) ^ (fl & 7))) << 4);
        }
#pragma unroll
    for (int mi = 0; mi < 4; ++mi)
#pragma unroll
        for (int kk = 0; kk < 2; ++kk)
            ao_[mi][kk] = 32768 + (((((wv & 1) * 4 + mi) * 2) + kk) << 10) + (lane << 4);

    f32x4 acc[4][4] = {};
    bf16x8 aF[4][2], bF[4][2];

#define STAGE(t, buf)                                                                \
    {                                                                                \
        const size_t bo = (size_t)((t) >> 3) * 307200 + (size_t)((t) & 7) * 128;     \
        const size_t ao = (size_t)(t) << 11;                                         \
        char* dB = dstB + (buf) * 49152;                                             \
        char* dA = dstA + (buf) * 49152;                                             \
        async16(srcB[0] + bo, dB);                                                   \
        async16(srcB[1] + bo, dB + 1024);                                            \
        async16(srcB[2] + bo, dB + 2048);                                            \
        async16(srcB[3] + bo, dB + 3072);                                            \
        async16(srcA[0] + ao, dA);                                                   \
        async16(srcA[1] + ao, dA + 1024);                                            \
    }
#define BODY(buf)                                                                    \
    {                                                                                \
        const char* Lb = lds + (buf) * 49152;                                        \
        _Pragma("unroll")                                                            \
        for (int mi = 0; mi < 4; ++mi) {                                             \
            aF[mi][0] = *(const bf16x8*)(Lb + ao_[mi][0]);                           \
            aF[mi][1] = *(const bf16x8*)(Lb + ao_[mi][1]);                           \
        }                                                                            \
        _Pragma("unroll")                                                            \
        for (int ni = 0; ni < 4; ++ni) {                                             \
            bF[ni][0] = *(const bf16x8*)(Lb + bo_[ni][0]);                           \
            bF[ni][1] = *(const bf16x8*)(Lb + bo_[ni][1]);                           \
        }                                                                            \
        __builtin_amdgcn_s_setprio(1);                                               \
        _Pragma("unroll")                                                            \
        for (int ni = 0; ni < 4; ++ni)                                               \
            _Pragma("unroll")                                                        \
            for (int mi = 0; mi < 4; ++mi)                                           \
                acc[mi][ni] = __builtin_amdgcn_mfma_f32_16x16x32_bf16(aF[mi][0], bF[ni][0], acc[mi][ni], 0, 0, 0); \
        _Pragma("unroll")                                                            \
        for (int ni = 0; ni < 4; ++ni)                                               \
            _Pragma("unroll")                                                        \
            for (int mi = 0; mi < 4; ++mi)                                           \
                acc[mi][ni] = __builtin_amdgcn_mfma_f32_16x16x32_bf16(aF[mi][1], bF[ni][1], acc[mi][ni], 0, 0, 0); \
        __builtin_amdgcn_s_setprio(0);                                               \
    }

    STAGE(0, 0);
    STAGE(1, 1);
    asm volatile("s_waitcnt vmcnt(6)" ::: "memory");   // buf0 landed (buf1 in flight)
    __builtin_amdgcn_s_barrier();
    for (int t = 0; t < 56; ++t) {
        const int buf = t & 1;
        BODY(buf);
        asm volatile("s_waitcnt vmcnt(0)" ::: "memory"); // STAGE(t+1) landed (1 K-tile old)
        __builtin_amdgcn_s_barrier();                    // all reads of buf complete block-wide
        if (t < 54) STAGE(t + 2, buf);                   // safe overwrite of buf
    }
#undef STAGE
#undef BODY

    // ---- epilogue: bias+relu, fused agg [identical to R6] ----
    const int quad4 = sq * 4;
#pragma unroll
    for (int mi = 0; mi < 4; ++mi) {
        const int cob = m0 + wm + mi * 16 + quad4;
        const float b0 = conv_b[cob + 0], b1 = conv_b[cob + 1],
                    b2 = conv_b[cob + 2], b3 = conv_b[cob + 3];
#pragma unroll
        for (int ni = 0; ni < 4; ++ni) {
            acc[mi][ni][0] = fmaxf(acc[mi][ni][0] + b0, 0.f);
            acc[mi][ni][1] = fmaxf(acc[mi][ni][1] + b1, 0.f);
            acc[mi][ni][2] = fmaxf(acc[mi][ni][2] + b2, 0.f);
            acc[mi][ni][3] = fmaxf(acc[mi][ni][3] + b3, 0.f);
        }
    }
    int nn[4];
#pragma unroll
    for (int ni = 0; ni < 4; ++ni) nn[ni] = nt2 * 256 + wn + ni * 16 + fl;
    const float* asg = assign + (size_t)b * 30000;
    const int s_ = ((fl & 1) << 3) | ((fl & 2) << 1) | ((fl & 4) >> 1) | ((fl & 8) >> 3);
    const int co_off = (s_ >> 2) * 16 + quad4 + (s_ & 3);    // 0..63 within wm half
    float red10[10];
    for (int k = 0; k < 10; ++k) {
        float av[4];
#pragma unroll
        for (int ni = 0; ni < 4; ++ni)
            av[ni] = (nn[ni] < 3000) ? asg[(size_t)k * 3000 + nn[ni]] : 0.f;
        float part[16];
#pragma unroll
        for (int mi = 0; mi < 4; ++mi)
#pragma unroll
            for (int r = 0; r < 4; ++r)
                part[mi * 4 + r] = av[0] * acc[mi][0][r] + av[1] * acc[mi][1][r]
                                 + av[2] * acc[mi][2][r] + av[3] * acc[mi][3][r];
#pragma unroll
        for (int bit = 0; bit < 4; ++bit) {
            const int off = 1 << bit;
            const int h = 8 >> bit;
            const bool hi = (fl >> bit) & 1;
#pragma unroll
            for (int jj = 0; jj < h; ++jj) {
                const float mine = hi ? part[jj + h] : part[jj];
                const float send = hi ? part[jj] : part[jj + h];
                part[jj] = mine + __shfl_xor(send, off, 64);
            }
        }
        red10[k] = part[0];
    }
    // deterministic cross-wave combine: all 8 waves park; waves 0,1 sum+atomic
    float* sagg = (float*)lds;                 // [wv 8][k 10][64]
    __syncthreads();
#pragma unroll
    for (int k = 0; k < 10; ++k) sagg[(wv * 10 + k) * 64 + co_off] = red10[k];
    __syncthreads();
    if (wv < 2) {
#pragma unroll
        for (int k = 0; k < 10; ++k) {
            const float v = sagg[((wv + 0) * 10 + k) * 64 + co_off]
                          + sagg[((wv + 2) * 10 + k) * 64 + co_off]
                          + sagg[((wv + 4) * 10 + k) * 64 + co_off]
                          + sagg[((wv + 6) * 10 + k) * 64 + co_off];
            atomicAdd(&agg[(size_t)(b * 10 + k) * 512 + m0 + wv * 64 + co_off], v);
        }
    }
}

// ---------------------------------------------------------------------------
// fc_fused: block 1024. [FROZEN]
// ---------------------------------------------------------------------------
__global__ __launch_bounds__(1024) void fc_fused(const float* __restrict__ agg,
                                                 const float* __restrict__ asum_part,
                                                 const float* __restrict__ centroids,
                                                 const float* __restrict__ fc_w,
                                                 const float* __restrict__ fc_b,
                                                 float* __restrict__ out) {
    __shared__ float res[4096];
    __shared__ float sasum[8];
    __shared__ float red2[16][4];
    __shared__ float scale[8];
    const int b = blockIdx.y;
    const int t = threadIdx.x;
    if (t < 8) {
        float s = 0.f;
#pragma unroll
        for (int p = 0; p < 48; ++p) s += asum_part[(p * 16 + b) * 10 + t];
        sasum[t] = s;
    }
    __syncthreads();
    const int b0 = t >> 9;                     // wave-uniform (0 or 1)
    float sqv[4] = {0.f, 0.f, 0.f, 0.f};
#pragma unroll
    for (int jj = 0; jj < 4; ++jj) {
        const int i = t + jj * 1024;
        const int k = b0 + jj * 2;
        const int c = i & 511;
        const float r = agg[(size_t)(b * 10 + k) * 512 + c] - sasum[k] * centroids[k * 512 + c];
        res[i] = r;
        sqv[jj] += r * r;
    }
    const int lane = t & 63, w = t >> 6;
#pragma unroll
    for (int jj = 0; jj < 4; ++jj) {
        float v = sqv[jj];
        for (int off = 32; off; off >>= 1) v += __shfl_xor(v, off, 64);
        if (lane == 0) red2[w][jj] = v;
    }
    __syncthreads();
    if (t < 8) {
        const int half = (t & 1) * 8;
        const int jj = t >> 1;
        float ss = 0.f;
#pragma unroll
        for (int i2 = 0; i2 < 8; ++i2) ss += red2[half + i2][jj];
        scale[t] = 1.f / fmaxf(sqrtf(ss), 1e-12f);
    }
    __syncthreads();

    const int col = t >> 5;
    const int ks = t & 31;
    const int co = blockIdx.x * 32 + col;
    const float4* w4 = (const float4*)(fc_w + (size_t)co * 4096);
    float acc = 0.f;
#pragma unroll 4
    for (int j2 = 0; j2 < 32; ++j2) {
        const int i = ks + 32 * j2;
        const float4 wv = w4[i];
        const float4 rv = *(const float4*)&res[i * 4];
        acc += (rv.x * wv.x + rv.y * wv.y + rv.z * wv.z + rv.w * wv.w) * scale[j2 >> 2];
    }
    acc += __shfl_down(acc, 16, 32);
    acc += __shfl_down(acc, 8, 32);
    acc += __shfl_down(acc, 4, 32);
    acc += __shfl_down(acc, 2, 32);
    acc += __shfl_down(acc, 1, 32);
    if (ks == 0) out[b * 512 + co] = fmaxf(acc + fc_b[co], 0.f);
}

// ---------------------------------------------------------------------------
// logit: block 1024. [FROZEN]
// ---------------------------------------------------------------------------
__global__ __launch_bounds__(1024) void logit_kernel(const float* __restrict__ emb,
                                                     const float* __restrict__ logit_w,
                                                     float* __restrict__ out) {
    __shared__ float se[512];
    const int gid = blockIdx.x;
    const int xcd = gid & 7;
    const int j = gid >> 3;
    const int otile = xcd * 3 + (j >> 4);
    const int b = j & 15;
    if (threadIdx.x < 512) se[threadIdx.x] = emb[b * 512 + threadIdx.x];
    __syncthreads();
    const int ol = threadIdx.x >> 2;
    const int ks = threadIdx.x & 3;
    const int o = otile * 256 + ol;
    if (o < 5994) {
        const float4* w4 = (const float4*)(logit_w + (size_t)o * 512);
        float acc = 0.f;
#pragma unroll 8
        for (int j2 = 0; j2 < 32; ++j2) {
            const int i = ks + 4 * j2;
            const float4 w = w4[i];
            acc += w.x * se[4 * i] + w.y * se[4 * i + 1] + w.z * se[4 * i + 2] + w.w * se[4 * i + 3];
        }
        acc += __shfl_down(acc, 2, 4);
        acc += __shfl_down(acc, 1, 4);
        if (ks == 0) out[8192 + b * 5994 + o] = acc;
    }
}

extern "C" void kernel_launch(void* const* d_in, const int* in_sizes, int n_in,
                              void* d_out, int out_size, void* d_ws, size_t ws_size,
                              hipStream_t stream) {
    (void)in_sizes; (void)n_in; (void)out_size; (void)ws_size;
    const float* x5       = (const float*)d_in[0];
    const float* conv_w   = (const float*)d_in[5];
    const float* conv_b   = (const float*)d_in[6];
    const float* cc_w     = (const float*)d_in[7];
    const float* cc_b     = (const float*)d_in[8];
    const float* centroids= (const float*)d_in[9];
    const float* fc_w     = (const float*)d_in[10];
    const float* fc_b     = (const float*)d_in[11];
    const float* logit_w  = (const float*)d_in[12];
    float* out = (float*)d_out;

    char* ws = (char*)d_ws;
    __hip_bfloat16* X3  = (__hip_bfloat16*)(ws);              // 78,643,200 B
    __hip_bfloat16* A2f = (__hip_bfloat16*)(ws + 78643200);   //  4,587,520 B (fragment-order)
    float* assign       = (float*)(ws + 83230720);            //  1,920,000 B
    float* asum_part    = (float*)(ws + 85150720);            //     30,720 B (48 partials)
    float* agg          = (float*)(ws + 85181440);            //    327,680 B

    pack_all<<<dim3(10880), 256, 0, stream>>>(x5, conv_w, cc_w, X3, A2f);
    scores_gemm<<<dim3(768), 256, 0, stream>>>(A2f, X3, cc_b, assign, asum_part, agg);
    conv_gemm<<<dim3(768), 512, 0, stream>>>(A2f, X3, conv_b, assign, agg);
    fc_fused<<<dim3(16, 16), 1024, 0, stream>>>(agg, asum_part, centroids, fc_w, fc_b, out);
    logit_kernel<<<dim3(384), 1024, 0, stream>>>(out, logit_w, out);
}

// Round 9
// 548.068 us; speedup vs baseline: 1.2153x; 1.2153x over previous
//
#include <hip/hip_runtime.h>
#include <hip/hip_bf16.h>

typedef __attribute__((ext_vector_type(8))) short bf16x8;
typedef __attribute__((ext_vector_type(4))) float f32x4;

__device__ __forceinline__ void async16(const void* g, void* l) {
    __builtin_amdgcn_global_load_lds(
        (const __attribute__((address_space(1))) unsigned int*)g,
        (__attribute__((address_space(3))) unsigned int*)l, 16, 0, 0);
}

// ---------------------------------------------------------------------------
// pack_all: one node = pack_x (10240 blocks) + pack_a (640 blocks). [FROZEN]
// ---------------------------------------------------------------------------
__global__ __launch_bounds__(256) void pack_all(const float* __restrict__ x5,
                                                const float* __restrict__ conv_w,
                                                const float* __restrict__ cc_w,
                                                __hip_bfloat16* __restrict__ X3,
                                                __hip_bfloat16* __restrict__ A2f) {
    __shared__ __align__(16) float smem[64 * 65];
    const int f = blockIdx.x;
    if (f < 10240) {
        // ---- pack_x ----
        float(*tile)[65] = (float(*)[65])smem;
        const int ct = f / 1280, r = f % 1280;
        const int wt = r >> 8, bh = r & 255;
        const int b = bh >> 4, h = bh & 15;
        const int w0 = wt * 64, c0 = ct * 64;
        const int lw = (threadIdx.x & 15) * 4;
        const int lc = threadIdx.x >> 4;
#pragma unroll
        for (int i = 0; i < 4; ++i) {
            const int c = lc + i * 16;
            const int w = w0 + lw;
            const float* src = &x5[((size_t)(b * 512 + c0 + c) * 16 + h) * 300 + w];
            float4 v = {0.f, 0.f, 0.f, 0.f};
            if (w + 3 < 300) v = *(const float4*)src;
            else {
                if (w < 300)     v.x = src[0];
                if (w + 1 < 300) v.y = src[1];
                if (w + 2 < 300) v.z = src[2];
            }
            *(float4*)&tile[c][lw] = v;
        }
        __syncthreads();
        const int sc = (threadIdx.x & 7) * 8;     // 8 channels -> 16B store
        const int sw0 = threadIdx.x >> 3;         // 0..31
#pragma unroll
        for (int i = 0; i < 2; ++i) {
            const int wl = sw0 + i * 32;
            const int w = w0 + wl;
            if (w < 300) {
                __hip_bfloat16 p[8];
#pragma unroll
                for (int j = 0; j < 8; ++j) p[j] = __float2bfloat16(tile[sc + j][wl]);
                *(uint4*)&X3[(((size_t)(b * 16 + h) * 300 + w)) * 512 + c0 + sc] = *(uint4*)p;
            }
        }
    } else {
        // ---- pack_a ----
        float* w = smem;
        const int co = f - 10240;                 // 0..639
        if (co < 522) {
            const float4* src = (co < 512) ? (const float4*)(conv_w + (size_t)co * 3584)
                                           : (const float4*)(cc_w + (size_t)(co - 512) * 3584);
            for (int i = threadIdx.x; i < 896; i += 256) *(float4*)&w[i * 4] = src[i];
        } else {
            for (int i = threadIdx.x; i < 3584; i += 256) w[i] = 0.f;
        }
        __syncthreads();
        const int g = co >> 4, fl = co & 15;
        for (int chunk = threadIdx.x; chunk < 448; chunk += 256) {
            const int kk0 = chunk * 8;
            const int kt = kk0 >> 5, sq = (kk0 >> 3) & 3;
            __hip_bfloat16 p[8];
#pragma unroll
            for (int j = 0; j < 8; ++j) {
                const int k = kk0 + j;
                p[j] = __float2bfloat16(w[(k & 511) * 7 + (k >> 9)]);
            }
            char* dst = (char*)A2f + (((size_t)g * 112 + kt) * 64 + sq * 16 + fl) * 16;
            *(uint4*)dst = *(uint4*)p;
        }
    }
}

// ---------------------------------------------------------------------------
// scores_gemm v2: 10 cc rows, M=16 MFMA, barrier-free + LDS-free staging.
// The 112 MFMAs were ONE serial dependency chain (acc->acc): each wave
// stalled a full MFMA latency per kt (latency-bound at 3 waves/SIMD). Now 4
// independent accumulator chains (kt mod 4), pairwise-summed at the end ->
// 4x ILP on the matrix pipe. Fused softmax/assign/asum + agg zero unchanged.
// grid 768 = 8 XCD * (2 b * 48 nt of 64 n); block 256 (4 waves * 16 n).
// ---------------------------------------------------------------------------
__global__ __launch_bounds__(256) void scores_gemm(
    const __hip_bfloat16* __restrict__ A2f, const __hip_bfloat16* __restrict__ X3,
    const float* __restrict__ cc_b, float* __restrict__ assign,
    float* __restrict__ asum_part, float* __restrict__ agg) {
    __shared__ float sred[4][4][4];            // [wave][sq][r] asum partials
    const int tid = threadIdx.x;
    const int wv = tid >> 6;
    const int lane = tid & 63;
    const int fl = lane & 15;
    const int sq = lane >> 4;
    const int gid = blockIdx.x;
    const int xcd = gid & 7;
    const int j = gid >> 3;                    // 0..95
    const int b = xcd * 2 + (j >= 48 ? 1 : 0);
    const int nt = j % 48;                     // 64-wide n tile

    // ---- agg zero (81920 floats over 768 blocks) ----
    {
        const int base = gid * 107;
        for (int i = tid; i < 107; i += 256) {
            const int idx = base + i;
            if (idx < 81920) agg[idx] = 0.f;
        }
    }

    const int n = nt * 64 + wv * 16 + fl;
    const int nc = n > 2999 ? 2999 : n;
    const char* gB = (const char*)X3 + ((size_t)(b * 4800 + nc)) * 1024 + sq * 16;
    const char* Af = (const char*)A2f + (((size_t)32 * 112) << 10) + ((size_t)lane << 4);

    f32x4 ac0 = {}, ac1 = {}, ac2 = {}, ac3 = {};
#pragma unroll 2
    for (int kt = 0; kt < 112; kt += 4) {
        const bf16x8 a0 = *(const bf16x8*)(Af + ((size_t)(kt + 0) << 10));
        const bf16x8 a1 = *(const bf16x8*)(Af + ((size_t)(kt + 1) << 10));
        const bf16x8 a2 = *(const bf16x8*)(Af + ((size_t)(kt + 2) << 10));
        const bf16x8 a3 = *(const bf16x8*)(Af + ((size_t)(kt + 3) << 10));
        const bf16x8 b0 = *(const bf16x8*)(gB + (size_t)((kt + 0) >> 4) * 307200 + (size_t)((kt + 0) & 15) * 64);
        const bf16x8 b1 = *(const bf16x8*)(gB + (size_t)((kt + 1) >> 4) * 307200 + (size_t)((kt + 1) & 15) * 64);
        const bf16x8 b2 = *(const bf16x8*)(gB + (size_t)((kt + 2) >> 4) * 307200 + (size_t)((kt + 2) & 15) * 64);
        const bf16x8 b3 = *(const bf16x8*)(gB + (size_t)((kt + 3) >> 4) * 307200 + (size_t)((kt + 3) & 15) * 64);
        ac0 = __builtin_amdgcn_mfma_f32_16x16x32_bf16(a0, b0, ac0, 0, 0, 0);
        ac1 = __builtin_amdgcn_mfma_f32_16x16x32_bf16(a1, b1, ac1, 0, 0, 0);
        ac2 = __builtin_amdgcn_mfma_f32_16x16x32_bf16(a2, b2, ac2, 0, 0, 0);
        ac3 = __builtin_amdgcn_mfma_f32_16x16x32_bf16(a3, b3, ac3, 0, 0, 0);
    }
    const f32x4 acc = (ac0 + ac1) + (ac2 + ac3);

    float s[4];
#pragma unroll
    for (int r = 0; r < 4; ++r) {
        const int k = sq * 4 + r;
        s[r] = (k < 10) ? (acc[r] + cc_b[k]) : -1e30f;
    }
    float mx = fmaxf(fmaxf(s[0], s[1]), fmaxf(s[2], s[3]));
    mx = fmaxf(mx, __shfl_xor(mx, 16, 64));
    mx = fmaxf(mx, __shfl_xor(mx, 32, 64));
    float e[4], es = 0.f;
#pragma unroll
    for (int r = 0; r < 4; ++r) {
        e[r] = (sq * 4 + r < 10) ? __expf(s[r] - mx) : 0.f;
        es += e[r];
    }
    es += __shfl_xor(es, 16, 64);
    es += __shfl_xor(es, 32, 64);
    const float inv = 1.f / es;
    const bool nval = (n < 3000);
    float pa[4];
#pragma unroll
    for (int r = 0; r < 4; ++r) {
        const int k = sq * 4 + r;
        const float a = e[r] * inv;
        pa[r] = nval ? a : 0.f;
        if (nval && k < 10) assign[(size_t)(b * 10 + k) * 3000 + n] = a;
    }
#pragma unroll
    for (int off = 1; off < 16; off <<= 1)
#pragma unroll
        for (int r = 0; r < 4; ++r) pa[r] += __shfl_xor(pa[r], off, 64);
    if (fl == 0) {
#pragma unroll
        for (int r = 0; r < 4; ++r) sred[wv][sq][r] = pa[r];
    }
    __syncthreads();
    if (tid < 10)
        asum_part[(nt * 16 + b) * 10 + tid] =
            sred[0][tid >> 2][tid & 3] + sred[1][tid >> 2][tid & 3] +
            sred[2][tid >> 2][tid & 3] + sred[3][tid >> 2][tid & 3];
}

// ---------------------------------------------------------------------------
// conv_gemm: proven R5 kernel (202us, MfmaUtil 41%, VGPR 64, 3 blocks/CU).
// Two phase-schedule variants (R6 lockstep: 224us; R7 free-run: VGPR spill,
// 339us) both lost to this structure -- at 64x64-per-wave the frag+acc regs
// exceed budget unless barriers shorten live ranges, and barriers kill the
// overlap. Multi-block residency (3/CU) provides the overlap for free.
// Implicit-im2col MFMA GEMM (m 0..511) with FUSED aggregation epilogue:
// transpose-reduce (15 shfl/k, lane fl owns slot bitrev4(fl)), cross-wave
// LDS combine, 1280 atomics/block.
//  - __launch_bounds__(256,4): 128-reg budget. Do NOT raise the min-waves
//    bound (a previous (256,6) forced acc spill -> 7.5 GB scratch).
// grid 1536 = 8 XCD * 48 (b,nt) * 4 m.
// ---------------------------------------------------------------------------
__global__ __launch_bounds__(256, 4) void conv_gemm(
    const __hip_bfloat16* __restrict__ A2f, const __hip_bfloat16* __restrict__ X3,
    const float* __restrict__ conv_b, const float* __restrict__ assign,
    float* __restrict__ agg) {
    __shared__ __align__(16) char lds[16384];   // B only: ph0 [0,8K) ph1 [8K,16K)
    const int tid = threadIdx.x;
    const int wv = tid >> 6;
    const int lane = tid & 63;

    // XCD-aware remap
    const int gid = blockIdx.x;
    const int xcd = gid & 7;
    const int j = gid >> 3;                    // 0..191
    const int nb = xcd * 48 + (j >> 2);        // 0..383
    const int m0 = (j & 3) * 128;              // 0,128,256,384
    const int b = nb / 24;
    const int nt = nb % 24;

    // ---- B staging (global -> LDS) ----
    const int row0 = wv * 16 + (lane >> 2);            // 0..63
    const int kseg = (lane & 3) ^ ((lane >> 3) & 3);   // XOR-swizzled source segment
    int n0 = nt * 128 + row0;      if (n0 > 2999) n0 = 2999;
    int n1 = nt * 128 + row0 + 64; if (n1 > 2999) n1 = 2999;
    const char* gB0 = (const char*)X3 + ((size_t)((b * 16 + n0 / 300) * 300 + n0 % 300)) * 1024 + (size_t)kseg * 16;
    const char* gB1 = (const char*)X3 + ((size_t)((b * 16 + n1 / 300) * 300 + n1 % 300)) * 1024 + (size_t)kseg * 16;
    char* lB = lds + wv * 1024 + lane * 16;            // +4096: rows 64..127

    // ---- fragment read offsets ----
    const int wm = (wv & 1) * 64;
    const int wn = (wv >> 1) * 64;
    const int fl = lane & 15;
    const int sq = lane >> 4;
    int boff[4];
#pragma unroll
    for (int i = 0; i < 4; ++i) {
        const int swz = (sq ^ ((fl >> 1) & 3)) * 16;
        boff[i] = (wn + i * 16 + fl) * 64 + swz;
    }
    // A fragment source (fragment-order A2f, coalesced)
    const char* Af = (const char*)A2f;
    const int gb = (m0 >> 4) + ((wv & 1) << 2);        // row-group base for this wave

    f32x4 acc[4][4] = {};
    bf16x8 aC[4], aN[4];

#define ISSUE_B(kt, ph)                                                                \
    {                                                                                  \
        const size_t badd = (size_t)((kt) >> 4) * 307200 + (size_t)((kt) & 15) * 64;   \
        async16(gB0 + badd, lB + (ph) * 8192);                                         \
        async16(gB1 + badd, lB + (ph) * 8192 + 4096);                                  \
    }
#define PRE_A(kt, arr)                                                                 \
    {                                                                                  \
        _Pragma("unroll")                                                              \
        for (int mi = 0; mi < 4; ++mi)                                                 \
            arr[mi] = *(const bf16x8*)(Af + (((size_t)(gb + mi) * 112 + (kt)) << 10) + (lane << 4)); \
    }
#define COMPUTE(ph, arr)                                                               \
    {                                                                                  \
        _Pragma("unroll")                                                              \
        for (int ni = 0; ni < 4; ++ni) {                                               \
            const bf16x8 bv = *(const bf16x8*)(lds + (ph) * 8192 + boff[ni]);          \
            _Pragma("unroll")                                                          \
            for (int mi = 0; mi < 4; ++mi)                                             \
                acc[mi][ni] = __builtin_amdgcn_mfma_f32_16x16x32_bf16(arr[mi], bv, acc[mi][ni], 0, 0, 0); \
        }                                                                              \
    }

    ISSUE_B(0, 0);
    PRE_A(0, aC);
    for (int kt = 0; kt < 112; kt += 2) {
        __syncthreads();                       // vmcnt(0) drain: B(kt) + aC landed
        ISSUE_B(kt + 1, 1);
        PRE_A(kt + 1, aN);
        COMPUTE(0, aC);
        __syncthreads();                       // B(kt+1) + aN landed; buf0 reads done
        if (kt < 110) { ISSUE_B(kt + 2, 0); PRE_A(kt + 2, aC); }
        COMPUTE(1, aN);
    }
#undef ISSUE_B
#undef PRE_A
#undef COMPUTE

    // ---- epilogue: bias+relu in-register, then fused agg ----
    const int quad4 = sq * 4;
#pragma unroll
    for (int mi = 0; mi < 4; ++mi) {
        const int cob = m0 + wm + mi * 16 + quad4;
        const float b0 = conv_b[cob + 0], b1 = conv_b[cob + 1],
                    b2 = conv_b[cob + 2], b3 = conv_b[cob + 3];
#pragma unroll
        for (int ni = 0; ni < 4; ++ni) {
            acc[mi][ni][0] = fmaxf(acc[mi][ni][0] + b0, 0.f);
            acc[mi][ni][1] = fmaxf(acc[mi][ni][1] + b1, 0.f);
            acc[mi][ni][2] = fmaxf(acc[mi][ni][2] + b2, 0.f);
            acc[mi][ni][3] = fmaxf(acc[mi][ni][3] + b3, 0.f);
        }
    }
    int nn[4];
#pragma unroll
    for (int ni = 0; ni < 4; ++ni) nn[ni] = nt * 128 + wn + ni * 16 + fl;
    const float* asg = assign + (size_t)b * 30000;
    // lane will own slot s = bitrev4(fl) after the transpose-reduce
    const int s_ = ((fl & 1) << 3) | ((fl & 2) << 1) | ((fl & 4) >> 1) | ((fl & 8) >> 3);
    const int co_off = (s_ >> 2) * 16 + quad4 + (s_ & 3);    // 0..63 within wm half
    float red10[10];
    for (int k = 0; k < 10; ++k) {
        float av[4];
#pragma unroll
        for (int ni = 0; ni < 4; ++ni)
            av[ni] = (nn[ni] < 3000) ? asg[(size_t)k * 3000 + nn[ni]] : 0.f;
        float part[16];
#pragma unroll
        for (int mi = 0; mi < 4; ++mi)
#pragma unroll
            for (int r = 0; r < 4; ++r)
                part[mi * 4 + r] = av[0] * acc[mi][0][r] + av[1] * acc[mi][1][r]
                                 + av[2] * acc[mi][2][r] + av[3] * acc[mi][3][r];
        // butterfly transpose-reduce over the 16 fl lanes: 8+4+2+1 = 15 shfl
#pragma unroll
        for (int bit = 0; bit < 4; ++bit) {
            const int off = 1 << bit;
            const int h = 8 >> bit;
            const bool hi = (fl >> bit) & 1;
#pragma unroll
            for (int jj = 0; jj < h; ++jj) {
                const float mine = hi ? part[jj + h] : part[jj];
                const float send = hi ? part[jj] : part[jj + h];
                part[jj] = mine + __shfl_xor(send, off, 64);
            }
        }
        red10[k] = part[0];
    }
    // cross-wave combine: waves 0,1 (wn=0) park in dead ph0 LDS; waves 2,3 add
    float* sagg = (float*)lds;                 // [2 wm-half][10 k][64 co_off]
    if (wv < 2) {
#pragma unroll
        for (int k = 0; k < 10; ++k) sagg[((wv * 10 + k) << 6) + co_off] = red10[k];
    }
    __syncthreads();
    if (wv >= 2) {
        const int wmh = wv & 1;
#pragma unroll
        for (int k = 0; k < 10; ++k) {
            const float v = red10[k] + sagg[((wmh * 10 + k) << 6) + co_off];
            atomicAdd(&agg[(size_t)(b * 10 + k) * 512 + m0 + wm + co_off], v);
        }
    }
}

// ---------------------------------------------------------------------------
// fc_fused: block 1024. [FROZEN]
// ---------------------------------------------------------------------------
__global__ __launch_bounds__(1024) void fc_fused(const float* __restrict__ agg,
                                                 const float* __restrict__ asum_part,
                                                 const float* __restrict__ centroids,
                                                 const float* __restrict__ fc_w,
                                                 const float* __restrict__ fc_b,
                                                 float* __restrict__ out) {
    __shared__ float res[4096];
    __shared__ float sasum[8];
    __shared__ float red2[16][4];
    __shared__ float scale[8];
    const int b = blockIdx.y;
    const int t = threadIdx.x;
    if (t < 8) {
        float s = 0.f;
#pragma unroll
        for (int p = 0; p < 48; ++p) s += asum_part[(p * 16 + b) * 10 + t];
        sasum[t] = s;
    }
    __syncthreads();
    const int b0 = t >> 9;                     // wave-uniform (0 or 1)
    float sqv[4] = {0.f, 0.f, 0.f, 0.f};
#pragma unroll
    for (int jj = 0; jj < 4; ++jj) {
        const int i = t + jj * 1024;
        const int k = b0 + jj * 2;
        const int c = i & 511;
        const float r = agg[(size_t)(b * 10 + k) * 512 + c] - sasum[k] * centroids[k * 512 + c];
        res[i] = r;
        sqv[jj] += r * r;
    }
    const int lane = t & 63, w = t >> 6;
#pragma unroll
    for (int jj = 0; jj < 4; ++jj) {
        float v = sqv[jj];
        for (int off = 32; off; off >>= 1) v += __shfl_xor(v, off, 64);
        if (lane == 0) red2[w][jj] = v;
    }
    __syncthreads();
    if (t < 8) {
        const int half = (t & 1) * 8;
        const int jj = t >> 1;
        float ss = 0.f;
#pragma unroll
        for (int i2 = 0; i2 < 8; ++i2) ss += red2[half + i2][jj];
        scale[t] = 1.f / fmaxf(sqrtf(ss), 1e-12f);
    }
    __syncthreads();

    const int col = t >> 5;
    const int ks = t & 31;
    const int co = blockIdx.x * 32 + col;
    const float4* w4 = (const float4*)(fc_w + (size_t)co * 4096);
    float acc = 0.f;
#pragma unroll 4
    for (int j2 = 0; j2 < 32; ++j2) {
        const int i = ks + 32 * j2;
        const float4 wv = w4[i];
        const float4 rv = *(const float4*)&res[i * 4];
        acc += (rv.x * wv.x + rv.y * wv.y + rv.z * wv.z + rv.w * wv.w) * scale[j2 >> 2];
    }
    acc += __shfl_down(acc, 16, 32);
    acc += __shfl_down(acc, 8, 32);
    acc += __shfl_down(acc, 4, 32);
    acc += __shfl_down(acc, 2, 32);
    acc += __shfl_down(acc, 1, 32);
    if (ks == 0) out[b * 512 + co] = fmaxf(acc + fc_b[co], 0.f);
}

// ---------------------------------------------------------------------------
// logit: block 1024. [FROZEN]
// ---------------------------------------------------------------------------
__global__ __launch_bounds__(1024) void logit_kernel(const float* __restrict__ emb,
                                                     const float* __restrict__ logit_w,
                                                     float* __restrict__ out) {
    __shared__ float se[512];
    const int gid = blockIdx.x;
    const int xcd = gid & 7;
    const int j = gid >> 3;
    const int otile = xcd * 3 + (j >> 4);
    const int b = j & 15;
    if (threadIdx.x < 512) se[threadIdx.x] = emb[b * 512 + threadIdx.x];
    __syncthreads();
    const int ol = threadIdx.x >> 2;
    const int ks = threadIdx.x & 3;
    const int o = otile * 256 + ol;
    if (o < 5994) {
        const float4* w4 = (const float4*)(logit_w + (size_t)o * 512);
        float acc = 0.f;
#pragma unroll 8
        for (int j2 = 0; j2 < 32; ++j2) {
            const int i = ks + 4 * j2;
            const float4 w = w4[i];
            acc += w.x * se[4 * i] + w.y * se[4 * i + 1] + w.z * se[4 * i + 2] + w.w * se[4 * i + 3];
        }
        acc += __shfl_down(acc, 2, 4);
        acc += __shfl_down(acc, 1, 4);
        if (ks == 0) out[8192 + b * 5994 + o] = acc;
    }
}

extern "C" void kernel_launch(void* const* d_in, const int* in_sizes, int n_in,
                              void* d_out, int out_size, void* d_ws, size_t ws_size,
                              hipStream_t stream) {
    (void)in_sizes; (void)n_in; (void)out_size; (void)ws_size;
    const float* x5       = (const float*)d_in[0];
    const float* conv_w   = (const float*)d_in[5];
    const float* conv_b   = (const float*)d_in[6];
    const float* cc_w     = (const float*)d_in[7];
    const float* cc_b     = (const float*)d_in[8];
    const float* centroids= (const float*)d_in[9];
    const float* fc_w     = (const float*)d_in[10];
    const float* fc_b     = (const float*)d_in[11];
    const float* logit_w  = (const float*)d_in[12];
    float* out = (float*)d_out;

    char* ws = (char*)d_ws;
    __hip_bfloat16* X3  = (__hip_bfloat16*)(ws);              // 78,643,200 B
    __hip_bfloat16* A2f = (__hip_bfloat16*)(ws + 78643200);   //  4,587,520 B (fragment-order)
    float* assign       = (float*)(ws + 83230720);            //  1,920,000 B
    float* asum_part    = (float*)(ws + 85150720);            //     30,720 B (48 partials)
    float* agg          = (float*)(ws + 85181440);            //    327,680 B

    pack_all<<<dim3(10880), 256, 0, stream>>>(x5, conv_w, cc_w, X3, A2f);
    scores_gemm<<<dim3(768), 256, 0, stream>>>(A2f, X3, cc_b, assign, asum_part, agg);
    conv_gemm<<<dim3(1536), 256, 0, stream>>>(A2f, X3, conv_b, assign, agg);
    fc_fused<<<dim3(16, 16), 1024, 0, stream>>>(agg, asum_part, centroids, fc_w, fc_b, out);
    logit_kernel<<<dim3(384), 1024, 0, stream>>>(out, logit_w, out);
}